// Round 1
// 206.858 us; speedup vs baseline: 1.0796x; 1.0796x over previous
//
#include <hip/hip_runtime.h>

// Causal linear attention (elu+1 feature map) — partition-coarsened MFMA scheme.
// N=4, L=4096, H=12, D=M=64.  L is split into P=16 partitions of 256 rows
// (= 4 chunks of C=64).  Per (n,h,partition):
//   k_psum : partition total KV^T (fp32 MFMA acc over 4 sub-chunks) + Ksum.
//   k_scanP: exclusive prefix scan over the 16 partitions (tiny).
//   k_fused: walks the partition's 4 chunks keeping running S in fp32 regs
//            (bf16 mirror in LDS for the Qf*S MFMA):
//              A = Qf Kf^T (masked);  O = Amask V + Qf S;  z = rowsum + Qf.Ksum
//            then S += KV^T(chunk).
// This cuts workspace HBM traffic ~204MB -> ~51MB vs the chunk-grained scheme.

#define NBATCH 4
#define LSEQ   4096
#define NHEAD  12
#define DDIM   64
#define LSTRIDE (NHEAD * DDIM)
#define NH     (NBATCH * NHEAD)
#define EPSF   1e-6f
#define CHUNK  64
#define NUMC   (LSEQ / CHUNK)
#define PPART  16               // partitions per sequence
#define CPP    (NUMC / PPART)   // chunks per partition = 4
#define SB     72               // LDS row stride in shorts (16B-aligned frags)

typedef __attribute__((ext_vector_type(8))) short bf16x8;
typedef __attribute__((ext_vector_type(4))) float f32x4;

__device__ __forceinline__ float phi(float x) { return x > 0.f ? x + 1.f : __expf(x); }

__device__ __forceinline__ unsigned short f2bf(float x) {
    union { float f; unsigned u; } v; v.f = x;
    unsigned r = v.u + 0x7fffu + ((v.u >> 16) & 1u);   // RNE
    return (unsigned short)(r >> 16);
}
__device__ __forceinline__ float bf2f(short s) {
    union { float f; unsigned u; } v; v.u = ((unsigned)(unsigned short)s) << 16;
    return v.f;
}
__device__ __forceinline__ uint2 pack4(float4 a) {
    uint2 r;
    r.x = (unsigned)f2bf(a.x) | ((unsigned)f2bf(a.y) << 16);
    r.y = (unsigned)f2bf(a.z) | ((unsigned)f2bf(a.w) << 16);
    return r;
}

// 4x4 fp32 transpose among lanes {lane^16, lane^32}.
__device__ __forceinline__ float4 xpose4(float4 x, int lane) {
    const bool b0 = (lane >> 4) & 1, b1 = (lane >> 5) & 1;
    float s0 = b0 ? x.x : x.y;
    float s1 = b0 ? x.z : x.w;
    s0 = __shfl_xor(s0, 16);
    s1 = __shfl_xor(s1, 16);
    float4 y;
    if (b0) { y.x = s0;  y.y = x.y; y.z = s1;  y.w = x.w; }
    else    { y.x = x.x; y.y = s0;  y.z = x.z; y.w = s1;  }
    float t0 = b1 ? y.x : y.z;
    float t1 = b1 ? y.y : y.w;
    t0 = __shfl_xor(t0, 32);
    t1 = __shfl_xor(t1, 32);
    float4 z;
    if (b1) { z.x = t0;  z.y = t1;  z.z = y.z; z.w = y.w; }
    else    { z.x = y.x; z.y = y.y; z.z = t0;  z.w = t1;  }
    return z;
}

// ---------------------------------------------------------------------------
// Kernel 1: partition totals.  KV^T[m][d] = sum_l V[l][m] Kf[l][d] over 256
// rows (4 sub-chunks, fp32 MFMA accumulation), Ksum[d] = sum_l Kf[l][d].
// ---------------------------------------------------------------------------
__global__ __launch_bounds__(256) void k_psum(const float* __restrict__ kin,
                                              const float* __restrict__ vin,
                                              float* __restrict__ kvws,
                                              float* __restrict__ ksws) {
    __shared__ short sKT[64 * SB];   // [d][l]
    __shared__ short sVT[64 * SB];   // [m][l]
    const int b = blockIdx.x, seq = b / PPART, p = b % PPART;
    const int n0 = seq / NHEAD, h0 = seq % NHEAD;
    const int t = threadIdx.x;
    const int lane = t & 63, w = t >> 6;
    const int nn = lane & 15, qq = lane >> 4;
    const int c4 = nn << 2;

    float4 kreg[4], vreg[4];
    auto LOADCC = [&](int cc) {
        const int gb = ((n0 * LSEQ + (p * CPP + cc) * CHUNK) * NHEAD + h0) * DDIM;
#pragma unroll
        for (int rep = 0; rep < 4; ++rep) {
            const int r16 = rep * 16 + 4 * w + qq;
            kreg[rep] = *(const float4*)(kin + gb + r16 * LSTRIDE + c4);
            vreg[rep] = *(const float4*)(vin + gb + r16 * LSTRIDE + c4);
        }
    };

    f32x4 S[4] = {{0,0,0,0},{0,0,0,0},{0,0,0,0},{0,0,0,0}};
    float ks = 0.f;
    LOADCC(0);
    for (int cc = 0; cc < CPP; ++cc) {
#pragma unroll
        for (int rep = 0; rep < 4; ++rep) {
            const int l0 = rep * 16 + 4 * w;
            float4 kk = kreg[rep];
            float4 kp = {phi(kk.x), phi(kk.y), phi(kk.z), phi(kk.w)};
            float4 kt = xpose4(kp, lane);
            *(uint2*)(sKT + (c4 + qq) * SB + l0) = pack4(kt);
            float4 vt = xpose4(vreg[rep], lane);
            *(uint2*)(sVT + (c4 + qq) * SB + l0) = pack4(vt);
        }
        __syncthreads();
        if (cc + 1 < CPP) LOADCC(cc + 1);   // prefetch: latency hides under MFMA
        const int rowM = 16 * w + nn;
        bf16x8 af0 = *(const bf16x8*)(sVT + rowM * SB + qq * 8);
        bf16x8 af1 = *(const bf16x8*)(sVT + rowM * SB + 32 + qq * 8);
#pragma unroll
        for (int ct = 0; ct < 4; ++ct) {
            bf16x8 bf0 = *(const bf16x8*)(sKT + (16 * ct + nn) * SB + qq * 8);
            bf16x8 bf1 = *(const bf16x8*)(sKT + (16 * ct + nn) * SB + 32 + qq * 8);
            S[ct] = __builtin_amdgcn_mfma_f32_16x16x32_bf16(af0, bf0, S[ct], 0, 0, 0);
            S[ct] = __builtin_amdgcn_mfma_f32_16x16x32_bf16(af1, bf1, S[ct], 0, 0, 0);
            if (ct == w) {   // wave-uniform: Ksum for d-band 16w..16w+15
                float s = 0.f;
#pragma unroll
                for (int j = 0; j < 8; ++j) s += bf2f(bf0[j]) + bf2f(bf1[j]);
                s += __shfl_xor(s, 16);
                s += __shfl_xor(s, 32);
                ks += s;
            }
        }
        __syncthreads();
    }
    float* kvb = kvws + (size_t)b * (DDIM * DDIM);
#pragma unroll
    for (int ct = 0; ct < 4; ++ct)
#pragma unroll
        for (int r = 0; r < 4; ++r)
            kvb[(16 * w + 4 * qq + r) * DDIM + 16 * ct + nn] = S[ct][r];
    if (qq == 0) ksws[b * DDIM + 16 * w + nn] = ks;
}

// ---------------------------------------------------------------------------
// Kernel 2: exclusive prefix scan over the 16 partitions (loads fully
// unrolled up-front so HBM latency is paid once, not serially).
// ---------------------------------------------------------------------------
__global__ __launch_bounds__(64) void k_scanP(float* __restrict__ kv,
                                              float* __restrict__ ksum) {
    const int bid = blockIdx.x;
    const int seq = bid >> 4, part = bid & 15;
    const int t = threadIdx.x;
    float4* base = (float4*)(kv + (size_t)seq * PPART * DDIM * DDIM) + part * 64 + t;
    float4 x[PPART];
#pragma unroll
    for (int c = 0; c < PPART; ++c) x[c] = base[c * (DDIM * DDIM / 4)];
    float4 S = {0.f, 0.f, 0.f, 0.f};
#pragma unroll
    for (int c = 0; c < PPART; ++c) {
        base[c * (DDIM * DDIM / 4)] = S;
        S.x += x[c].x; S.y += x[c].y; S.z += x[c].z; S.w += x[c].w;
    }
    if (part == 0) {
        float* kb = ksum + (size_t)seq * PPART * DDIM + t;
        float xs[PPART];
#pragma unroll
        for (int c = 0; c < PPART; ++c) xs[c] = kb[c * DDIM];
        float s = 0.f;
#pragma unroll
        for (int c = 0; c < PPART; ++c) { kb[c * DDIM] = s; s += xs[c]; }
    }
}

// ---------------------------------------------------------------------------
// Kernel 3: fused per-partition output.  Walks 4 chunks; S held as fp32 in
// registers (MFMA C layout), mirrored to bf16 LDS for the Qf*S matmul.
// ---------------------------------------------------------------------------
__global__ __launch_bounds__(256, 3) void k_fused(const float* __restrict__ qin,
                                                  const float* __restrict__ kin,
                                                  const float* __restrict__ vin,
                                                  const float* __restrict__ kvws,
                                                  const float* __restrict__ ksws,
                                                  float* __restrict__ out) {
    __shared__ short sQ [64 * SB];   // [i][d]
    __shared__ short sKA[64 * SB];   // [j][d] -> reused as Amask [i][l]
    __shared__ short sKT[64 * SB];   // [d][l]
    __shared__ short sVT[64 * SB];   // [m][l]
    __shared__ short sST[64 * SB];   // [m][d]  (S^T layout: rows m, cols d)
    __shared__ float sKs[64];
    __shared__ float sZq[64];

    const int b = blockIdx.x, seq = b / PPART, p = b % PPART;
    const int n0 = seq / NHEAD, h0 = seq % NHEAD;
    const int t = threadIdx.x;
    const int lane = t & 63, w = t >> 6;
    const int nn = lane & 15, qq = lane >> 4;
    const int c4 = nn << 2;

    if (t < 64) sKs[t] = ksws[b * DDIM + t];

    // Exclusive partition-prefix S: fp32 into registers + bf16 mirror in LDS.
    const float* Sg = kvws + (size_t)b * (DDIM * DDIM);
    f32x4 Sreg[4];
#pragma unroll
    for (int ct = 0; ct < 4; ++ct) {
#pragma unroll
        for (int r = 0; r < 4; ++r) {
            const float sv = Sg[(16 * w + 4 * qq + r) * DDIM + 16 * ct + nn];
            Sreg[ct][r] = sv;
            sST[(16 * w + 4 * qq + r) * SB + 16 * ct + nn] = (short)f2bf(sv);
        }
    }

    float4 qreg[4], kreg[4], vreg[4];
    auto LOADCC = [&](int cc) {
        const int gb = ((n0 * LSEQ + (p * CPP + cc) * CHUNK) * NHEAD + h0) * DDIM;
#pragma unroll
        for (int rep = 0; rep < 4; ++rep) {
            const int r16 = rep * 16 + 4 * w + qq;
            qreg[rep] = *(const float4*)(qin + gb + r16 * LSTRIDE + c4);
            kreg[rep] = *(const float4*)(kin + gb + r16 * LSTRIDE + c4);
            vreg[rep] = *(const float4*)(vin + gb + r16 * LSTRIDE + c4);
        }
    };
    LOADCC(0);

    for (int cc = 0; cc < CPP; ++cc) {
        const int gbase = ((n0 * LSEQ + (p * CPP + cc) * CHUNK) * NHEAD + h0) * DDIM;
        // ---- stage chunk into LDS ----
#pragma unroll
        for (int rep = 0; rep < 4; ++rep) {
            const int row = rep * 16 + 4 * w + qq;
            const int l0 = rep * 16 + 4 * w;
            float4 qv = qreg[rep];
            float4 qp = {phi(qv.x), phi(qv.y), phi(qv.z), phi(qv.w)};
            *(uint2*)(sQ + row * SB + c4) = pack4(qp);
            float4 kk = kreg[rep];
            float4 kp = {phi(kk.x), phi(kk.y), phi(kk.z), phi(kk.w)};
            *(uint2*)(sKA + row * SB + c4) = pack4(kp);
            float4 kt = xpose4(kp, lane);
            *(uint2*)(sKT + (c4 + qq) * SB + l0) = pack4(kt);
            float4 vt = xpose4(vreg[rep], lane);
            *(uint2*)(sVT + (c4 + qq) * SB + l0) = pack4(vt);
        }
        __syncthreads();   // S1

        // ---- Phase A: A = Qf Kf^T, mask + rowsum; zq from old Ksum prefix ----
        const int rowA = 16 * w + nn;
        bf16x8 qf0 = *(const bf16x8*)(sQ + rowA * SB + qq * 8);
        bf16x8 qf1 = *(const bf16x8*)(sQ + rowA * SB + 32 + qq * 8);
        float am[4][4];
        float zrow[4] = {0.f, 0.f, 0.f, 0.f};
#pragma unroll
        for (int ct = 0; ct < 4; ++ct) {
            bf16x8 kf0 = *(const bf16x8*)(sKA + (16 * ct + nn) * SB + qq * 8);
            bf16x8 kf1 = *(const bf16x8*)(sKA + (16 * ct + nn) * SB + 32 + qq * 8);
            f32x4 acc = {0.f, 0.f, 0.f, 0.f};
            acc = __builtin_amdgcn_mfma_f32_16x16x32_bf16(qf0, kf0, acc, 0, 0, 0);
            acc = __builtin_amdgcn_mfma_f32_16x16x32_bf16(qf1, kf1, acc, 0, 0, 0);
#pragma unroll
            for (int r = 0; r < 4; ++r) {
                const int ri = 16 * w + 4 * qq + r, cj = 16 * ct + nn;
                const float mval = (cj <= ri) ? acc[r] : 0.f;
                am[ct][r] = mval;
                zrow[r] += mval;
            }
        }
#pragma unroll
        for (int r = 0; r < 4; ++r) {
            float s = zrow[r];
            s += __shfl_xor(s, 1); s += __shfl_xor(s, 2);
            s += __shfl_xor(s, 4); s += __shfl_xor(s, 8);
            zrow[r] = s;
        }
        float zq = 0.f;
#pragma unroll
        for (int j = 0; j < 8; ++j) {
            zq += bf2f(qf0[j]) * sKs[qq * 8 + j];
            zq += bf2f(qf1[j]) * sKs[32 + qq * 8 + j];
        }
        zq += __shfl_xor(zq, 16);
        zq += __shfl_xor(zq, 32);

        __syncthreads();   // S2: K reads + sKs reads done
        if (qq == 0) sZq[16 * w + nn] = zq;
#pragma unroll
        for (int ct = 0; ct < 4; ++ct)
#pragma unroll
            for (int r = 0; r < 4; ++r)
                sKA[(16 * w + 4 * qq + r) * SB + 16 * ct + nn] = (short)f2bf(am[ct][r]);
        __syncthreads();   // S3: Amask + sZq visible

        if (cc + 1 < CPP) LOADCC(cc + 1);   // prefetch next chunk under B/C

        // ---- Phases B/C + KV^T accumulate ----
        f32x4 o[4] = {{0,0,0,0},{0,0,0,0},{0,0,0,0},{0,0,0,0}};
        bf16x8 af0 = *(const bf16x8*)(sKA + rowA * SB + qq * 8);
        bf16x8 af1 = *(const bf16x8*)(sKA + rowA * SB + 32 + qq * 8);
        bf16x8 av0 = *(const bf16x8*)(sVT + rowA * SB + qq * 8);
        bf16x8 av1 = *(const bf16x8*)(sVT + rowA * SB + 32 + qq * 8);
        float ksc = 0.f;
#pragma unroll
        for (int ct = 0; ct < 4; ++ct) {
            bf16x8 vf0 = *(const bf16x8*)(sVT + (16 * ct + nn) * SB + qq * 8);
            bf16x8 vf1 = *(const bf16x8*)(sVT + (16 * ct + nn) * SB + 32 + qq * 8);
            o[ct] = __builtin_amdgcn_mfma_f32_16x16x32_bf16(af0, vf0, o[ct], 0, 0, 0);
            o[ct] = __builtin_amdgcn_mfma_f32_16x16x32_bf16(af1, vf1, o[ct], 0, 0, 0);
            bf16x8 sf0 = *(const bf16x8*)(sST + (16 * ct + nn) * SB + qq * 8);
            bf16x8 sf1 = *(const bf16x8*)(sST + (16 * ct + nn) * SB + 32 + qq * 8);
            o[ct] = __builtin_amdgcn_mfma_f32_16x16x32_bf16(qf0, sf0, o[ct], 0, 0, 0);
            o[ct] = __builtin_amdgcn_mfma_f32_16x16x32_bf16(qf1, sf1, o[ct], 0, 0, 0);
            bf16x8 kt0 = *(const bf16x8*)(sKT + (16 * ct + nn) * SB + qq * 8);
            bf16x8 kt1 = *(const bf16x8*)(sKT + (16 * ct + nn) * SB + 32 + qq * 8);
            Sreg[ct] = __builtin_amdgcn_mfma_f32_16x16x32_bf16(av0, kt0, Sreg[ct], 0, 0, 0);
            Sreg[ct] = __builtin_amdgcn_mfma_f32_16x16x32_bf16(av1, kt1, Sreg[ct], 0, 0, 0);
            if (ct == w) {   // chunk Ksum for d-band 16w..16w+15
                float s = 0.f;
#pragma unroll
                for (int j = 0; j < 8; ++j) s += bf2f(kt0[j]) + bf2f(kt1[j]);
                s += __shfl_xor(s, 16);
                s += __shfl_xor(s, 32);
                ksc = s;
            }
        }

#pragma unroll
        for (int r = 0; r < 4; ++r) {
            const int ri = 16 * w + 4 * qq + r;
            const float z = zrow[r] + sZq[ri] + EPSF;
            const float invz = 1.f / z;
#pragma unroll
            for (int ct = 0; ct < 4; ++ct)
                out[gbase + ri * LSTRIDE + 16 * ct + nn] = o[ct][r] * invz;
        }
        __syncthreads();   // S4: all reads of old sST / sVT / sKT / sKA done
        // refresh bf16 S mirror + Ksum prefix for next chunk
#pragma unroll
        for (int ct = 0; ct < 4; ++ct)
#pragma unroll
            for (int r = 0; r < 4; ++r)
                sST[(16 * w + 4 * qq + r) * SB + 16 * ct + nn] = (short)f2bf(Sreg[ct][r]);
        if (qq == 0) sKs[16 * w + nn] += ksc;
    }
}

// ---------------------------------------------------------------------------
// Fallback (tiny ws): fully sequential per-sequence scan, fp32, no workspace.
// ---------------------------------------------------------------------------
__global__ __launch_bounds__(64) void k_seq(const float* __restrict__ qin,
                                            const float* __restrict__ kin,
                                            const float* __restrict__ vin,
                                            float* __restrict__ out) {
    const int seq = blockIdx.x;
    const int n = seq / NHEAD, h = seq % NHEAD;
    const int lane = threadIdx.x;
    float Scol[DDIM];
#pragma unroll
    for (int d = 0; d < DDIM; ++d) Scol[d] = 0.0f;
    float kc = 0.0f;
    __shared__ float qk[2 * DDIM];
    int base = (n * LSEQ * NHEAD + h) * DDIM + lane;
    for (int i = 0; i < LSEQ; ++i) {
        float qval = phi(qin[base]);
        float kval = phi(kin[base]);
        float vval = vin[base];
        kc += kval;
        float zp = qval * kc;
#pragma unroll
        for (int off = 32; off > 0; off >>= 1) zp += __shfl_xor(zp, off, 64);
        float z = zp + EPSF;
        qk[2 * lane] = kval;
        qk[2 * lane + 1] = qval;
        __syncthreads();
        const float4* qk4 = (const float4*)qk;
        float acc = 0.0f;
#pragma unroll
        for (int d2 = 0; d2 < DDIM / 2; ++d2) {
            float4 t0 = qk4[d2];
            int d = 2 * d2;
            Scol[d]     += t0.x * vval;  acc += t0.y * Scol[d];
            Scol[d + 1] += t0.z * vval;  acc += t0.w * Scol[d + 1];
        }
        out[base] = acc / z;
        base += LSTRIDE;
        __syncthreads();
    }
}

// ---------------------------------------------------------------------------
extern "C" void kernel_launch(void* const* d_in, const int* in_sizes, int n_in,
                              void* d_out, int out_size, void* d_ws, size_t ws_size,
                              hipStream_t stream) {
    const float* q = (const float*)d_in[0];
    const float* k = (const float*)d_in[1];
    const float* v = (const float*)d_in[2];
    float* out = (float*)d_out;
    float* ws  = (float*)d_ws;

    const size_t need = (size_t)NH * PPART * (DDIM * DDIM + DDIM) * sizeof(float);
    if (ws_size >= need) {
        float* kv   = ws;
        float* ksum = ws + (size_t)NH * PPART * DDIM * DDIM;
        k_psum <<<NH * PPART, 256, 0, stream>>>(k, v, kv, ksum);
        k_scanP<<<NH * PPART,  64, 0, stream>>>(kv, ksum);
        k_fused<<<NH * PPART, 256, 0, stream>>>(q, k, v, kv, ksum, out);
    } else {
        k_seq<<<NH, 64, 0, stream>>>(q, k, v, out);
    }
}